// Round 9
// baseline (157.928 us; speedup 1.0000x reference)
//
#include <hip/hip_runtime.h>
#include <hip/hip_fp16.h>

// Problem constants
#define NN    256   // NUM_NODES
#define SS    4     // NUM_FSM_STATES
#define TT    3     // NUM_EDGE_TYPES
#define VV    4     // NUM_VARIANTS
#define NTY   8     // NUM_NODE_TYPES
#define NAC   15    // n_actions = T*S + 3
#define CAPG  48    // max packed pair-groups per col (96 edges; deg~Poi(38.4))
#define CAPE  (CAPG * 2)
#define ROWB  40    // bytes per tmp row (12 halves used + pad) -- r1-verified
#define ZROWB (NN * ROWB)       // zero pad row byte offset = 10240 (fits u16)
#define BUFB  (ZROWB + ROWB)    // bytes per tmp buffer = 10280 (8-aligned)
#define ZPK   ((unsigned)ZROWB | ((unsigned)ZROWB << 16))
#define GMR   16    // per-thread (per-parity-half) group regs; covers wave-max ~14

typedef _Float16 h2v __attribute__((ext_vector_type(2)));

#if defined(__has_builtin)
#if __has_builtin(__builtin_amdgcn_fdot2)
#define HAVE_FDOT2 1
#endif
#endif

static __device__ __forceinline__ unsigned ph2(float a, float b) {
    union { __half2 h; unsigned u; } c;
    c.h = __floats2half2_rn(a, b);
    return c.u;
}
static __device__ __forceinline__ h2v bch2(unsigned u) {
    union { unsigned u; h2v h; } c; c.u = u; return c.h;
}
static __device__ __forceinline__ float2 h2f2(unsigned u) {
    union { unsigned u; __half2 h; } c; c.u = u; return __half22float2(c.h);
}

// DPP-based lane combine: x + x[permuted lane], pure VALU (no ds_bpermute).
// quad_perm [1,0,3,2] = 0xB1 (xor1), [2,3,0,1] = 0x4E (xor2),
// row_ror:4 = 0x124, row_ror:8 = 0x128 (bijective within 16-lane row ->
// full-row sum in every lane), row_bcast15 = 0x142 (lane15->16..31,
// lane31->32..47, lane47->48..63), row_bcast31 = 0x143 (lane31->32..63).
// After ror stages + bcast15 + bcast31, lane 63 holds the 64-lane total
// (lanes 32..47 hold garbage -- never read).  bound_ctrl=true: no-src -> 0.
#define DPPADD(x, ctrl)                                                       \
    ((x) + __int_as_float(__builtin_amdgcn_update_dpp(                        \
               0, __float_as_int(x), (ctrl), 0xF, 0xF, true)))

// ---------------------------------------------------------------------------
// Setup (r5-verified):
//   blocks 0..767      : inv_deg row sums (coalesced, wave+LDS reduce)
//   blocks 768..831    : per-col edge build, 4 cols/block via float4 reads
//   block  832         : routing softmax
__global__ void k_setup(const float* __restrict__ adj,
                        const float* __restrict__ lrp,
                        float* __restrict__ inv_deg,
                        float* __restrict__ pol,
                        unsigned* __restrict__ epk,
                        int* __restrict__ gcnt) {
    const int b = blockIdx.x;
    const int tid = threadIdx.x;

    if (b < TT * NN) {
        __shared__ float wsum[4];
        float s = adj[(size_t)b * NN + tid];
#pragma unroll
        for (int off = 32; off > 0; off >>= 1) s += __shfl_down(s, off, 64);
        if ((tid & 63) == 0) wsum[tid >> 6] = s;
        __syncthreads();
        if (tid == 0)
            inv_deg[b] = 1.0f / fmaxf(wsum[0] + wsum[1] + wsum[2] + wsum[3], 1.0f);
    } else if (b < TT * NN + 64) {
        // edge lists for 4 columns: thread row=tid tests (t,tid,c4..c4+3)
        __shared__ int cnt[4];
        __shared__ unsigned short offs[4][CAPE + 2];
        const int c4 = (b - TT * NN) * 4;
        if (tid < 4) cnt[tid] = 0;
        __syncthreads();
#pragma unroll
        for (int t = 0; t < TT; t++) {
            const float4 a4 = *(const float4*)(adj + ((size_t)t * NN + tid) * NN + c4);
            const float av[4] = {a4.x, a4.y, a4.z, a4.w};
#pragma unroll
            for (int c = 0; c < 4; c++) {
                if (av[c] != 0.f) {
                    int idx = atomicAdd(&cnt[c], 1);
                    if (idx < CAPE) offs[c][idx] = (unsigned short)(tid * ROWB + t * 8);
                }
            }
        }
        __syncthreads();
        const int c    = tid >> 6;       // one wave per column
        const int lane = tid & 63;
        int cc = cnt[c]; if (cc > CAPE) cc = CAPE;
        if (lane == 0 && (cc & 1)) offs[c][cc] = (unsigned short)ZROWB;  // pad odd
        __syncthreads();
        const int g = (cc + 1) >> 1;
        for (int gg = lane; gg < g; gg += 64)
            epk[(size_t)gg * NN + (c4 + c)] =
                (unsigned)offs[c][2 * gg] | ((unsigned)offs[c][2 * gg + 1] << 16);
        if (lane == 0) gcnt[c4 + c] = g;
    } else {
        if (tid < VV * NTY * SS) {
            float x[NAC]; float m = -3.4e38f;
#pragma unroll
            for (int a = 0; a < NAC; a++) { x[a] = lrp[tid * NAC + a]; m = fmaxf(m, x[a]); }
            float ssum = 0.f;
#pragma unroll
            for (int a = 0; a < NAC; a++) { x[a] = __expf(x[a] - m); ssum += x[a]; }
            float inv = 1.f / ssum;
#pragma unroll
            for (int a = 0; a < NAC; a++) pol[tid * NAC + a] = x[a] * inv;
        }
    }
}

// ---------------------------------------------------------------------------
// Degree sort (r5-verified, trivial): counting sort of the 256 cols by group
// count (ascending).  perm[rank] = col.
__global__ void k_sort(const int* __restrict__ gcnt, int* __restrict__ perm) {
    __shared__ int base[64];
    const int tid = threadIdx.x;
    if (tid < 64) base[tid] = 0;
    __syncthreads();
    const int g = gcnt[tid] & 63;
    atomicAdd(&base[g], 1);          // histogram
    __syncthreads();
    if (tid == 0) {
        int s = 0;
#pragma unroll
        for (int b = 0; b < 64; b++) { int c = base[b]; base[b] = s; s += c; }
    }
    __syncthreads();
    const int pos = atomicAdd(&base[g], 1);   // cursor within bin
    perm[pos] = tid;
}

// ---------------------------------------------------------------------------
// Main loop: grid 512 = (e,i); block 512 threads = 2 threads per col.
// r8 base (95.7us): degree-sorted cols, pre-split resident gather addresses,
// x2-unrolled step loop (parity as ds immediate), DPP bj-reduce/d-combine,
// b64+b32 phase-A writes.
// This round:
//  - chunk-4 gather: 8 b64 loads in flight per scalar branch (was 4)
//  - bj reduce fully DPP (row_bcast15/31 replace the last 2 ds_bpermute
//    shuffles); wave total lands in lane 63
__global__ __launch_bounds__(512, 2) void k_main(
    const float* __restrict__ vw,
    const int* __restrict__ node_types,
    const float* __restrict__ pol,
    const float* __restrict__ inv_deg,
    const unsigned* __restrict__ epk,
    const int* __restrict__ gcnt,
    const int* __restrict__ perm,
    const int* __restrict__ steps_p,
    float* __restrict__ out)
{
    const int i    = blockIdx.x & 255;
    const int e    = blockIdx.x >> 8;
    const int tid  = threadIdx.x;
    const int col  = perm[tid >> 1];    // degree-sorted column assignment
    const int h    = tid & 1;
    const int lane = tid & 63;
    const int wv   = tid >> 6;          // 8 waves
    const int steps = steps_p[0];

    __shared__ __align__(16) char tmpb[2 * BUFB];   // 20.6 KB
    __shared__ __align__(16) float backp[2][8];

    if (tid < 20) {
        int pb = tid / 10, w = tid % 10;
        ((unsigned*)(tmpb + pb * BUFB + ZROWB))[w] = 0u;
    }

    // --- per-(col,half) mixed policy slice, pre-scaled by inv_deg ---
    const float4 w4 = *(const float4*)(vw + ((size_t)i * NN + col) * VV);
    const float wvv[VV] = {w4.x, w4.y, w4.z, w4.w};
    const int ntj = node_types[col];
    const int ab  = h * 6;              // this half's action base
    float pm6[SS][6], pcb[SS];
#pragma unroll
    for (int s = 0; s < SS; s++) {
        pcb[s] = 0.f;
#pragma unroll
        for (int a = 0; a < 6; a++) pm6[s][a] = 0.f;
    }
#pragma unroll
    for (int v = 0; v < VV; v++) {
        const float* pr = pol + (size_t)(v * NTY + ntj) * SS * NAC;
#pragma unroll
        for (int s = 0; s < SS; s++) {
            const float* p = pr + s * NAC;
#pragma unroll
            for (int a = 0; a < 6; a++) pm6[s][a] = fmaf(wvv[v], p[ab + a], pm6[s][a]);
            pcb[s] = fmaf(wvv[v], p[12 + h], pcb[s]);   // h0: accept, h1: back
        }
    }
    {
        float invd[TT];
#pragma unroll
        for (int t = 0; t < TT; t++) invd[t] = inv_deg[t * NN + col];
#pragma unroll
        for (int s = 0; s < SS; s++)
#pragma unroll
            for (int a = 0; a < 6; a++) pm6[s][a] *= invd[(ab + a) >> 2];
    }

    float D0 = (0 == e && col == i) ? 1.f : 0.f;
    float D1 = (1 == e && col == i) ? 1.f : 0.f;
    float D2 = 0.f, D3 = 0.f;
    float acc = 0.f;

    // --- this half's edge list (groups with parity h), pre-split addresses ---
    const int g_all = gcnt[col];
    const int ch = (g_all - h + 1) >> 1;     // my group count
    int km = ch;
#pragma unroll
    for (int off = 32; off > 0; off >>= 1) {
        int o = __shfl_xor(km, off, 64);
        km = o > km ? o : km;
    }
    const int kmax = __builtin_amdgcn_readfirstlane(km);   // wave-uniform

    unsigned offA[GMR], offB[GMR];      // 32 VGPR: LDS byte offsets, base-free
#pragma unroll
    for (int k = 0; k < GMR; k++) {
        unsigned pk = epk[(size_t)(2 * k + h) * NN + col];  // in-bounds; junk past g_all
        pk = (2 * k + h < g_all) ? pk : ZPK;                // junk reads zero row (bcast)
        offA[k] = pk & 0xffffu;
        offB[k] = pk >> 16;
    }

    const h2v S10 = {(_Float16)1.0f, (_Float16)0.0f};
    const h2v S01 = {(_Float16)0.0f, (_Float16)1.0f};
    // phase-A write addresses (branch-free split): b64 at +16h, b32 at +8+4h
    char* const myrowA = tmpb + col * ROWB + 16 * h;   // 8-aligned both h
    char* const myrowB = tmpb + col * ROWB + 8 + 4 * h;

#define STEP_BODY(PAR)                                                        \
    {                                                                         \
        float r4 = D0 * pcb[0];                                               \
        r4 = fmaf(D1, pcb[1], r4); r4 = fmaf(D2, pcb[2], r4);                 \
        r4 = fmaf(D3, pcb[3], r4);                                            \
        if (h == 0) acc += r4;                                                \
        float bj = h ? r4 : 0.f;                                              \
        float tv[6];                                                          \
        _Pragma("unroll")                                                     \
        for (int a = 0; a < 6; a++) {                                         \
            float x = D0 * pm6[0][a];                                         \
            x = fmaf(D1, pm6[1][a], x);                                       \
            x = fmaf(D2, pm6[2][a], x);                                       \
            x = fmaf(D3, pm6[3][a], x);                                       \
            tv[a] = x;                                                        \
        }                                                                     \
        {                                                                     \
            const unsigned wx = ph2(tv[0], tv[1]);                            \
            const unsigned wy = ph2(tv[2], tv[3]);                            \
            const unsigned wz = ph2(tv[4], tv[5]);                            \
            const unsigned lo = h ? wy : wx;                                  \
            const unsigned hi = h ? wz : wy;                                  \
            const unsigned bb = h ? wx : wz;                                  \
            *(unsigned long long*)(myrowA + (PAR) * BUFB) =                   \
                (unsigned long long)lo | ((unsigned long long)hi << 32);      \
            *(unsigned*)(myrowB + (PAR) * BUFB) = bb;                         \
        }                                                                     \
        bj = DPPADD(bj, 0xB1);    /* xor1 (quad_perm)            */           \
        bj = DPPADD(bj, 0x4E);    /* xor2 (quad_perm)            */           \
        bj = DPPADD(bj, 0x124);   /* row_ror:4                   */           \
        bj = DPPADD(bj, 0x128);   /* row_ror:8 -> row sums       */           \
        bj = DPPADD(bj, 0x142);   /* row_bcast15: chain rows     */           \
        bj = DPPADD(bj, 0x143);   /* row_bcast31: lane63 = total */           \
        if (lane == 63) backp[PAR][wv] = bj;                                  \
        __syncthreads();                                                      \
        float d0a = 0.f, d1a = 0.f, d2a = 0.f, d3a = 0.f;                     \
        float d0b = 0.f, d1b = 0.f, d2b = 0.f, d3b = 0.f;                     \
        _Pragma("unroll")                                                     \
        for (int kc = 0; kc < GMR; kc += 4) {                                 \
            if (kc < kmax) {   /* 8 b64 loads in flight per branch */         \
                const uint2 qA0 = *(const uint2*)(tmpb + (PAR) * BUFB + offA[kc]);     \
                const uint2 qA1 = *(const uint2*)(tmpb + (PAR) * BUFB + offB[kc]);     \
                const uint2 qB0 = *(const uint2*)(tmpb + (PAR) * BUFB + offA[kc + 1]); \
                const uint2 qB1 = *(const uint2*)(tmpb + (PAR) * BUFB + offB[kc + 1]); \
                const uint2 qC0 = *(const uint2*)(tmpb + (PAR) * BUFB + offA[kc + 2]); \
                const uint2 qC1 = *(const uint2*)(tmpb + (PAR) * BUFB + offB[kc + 2]); \
                const uint2 qD0 = *(const uint2*)(tmpb + (PAR) * BUFB + offA[kc + 3]); \
                const uint2 qD1 = *(const uint2*)(tmpb + (PAR) * BUFB + offB[kc + 3]); \
                GATHER8(qA0, qA1, a)                                          \
                GATHER8(qB0, qB1, b)                                          \
                GATHER8(qC0, qC1, a)                                          \
                GATHER8(qD0, qD1, b)                                          \
            }                                                                 \
        }                                                                     \
        for (int k = GMR; k < kmax; k++) {                                    \
            unsigned pk = epk[(size_t)(2 * k + h) * NN + col];                \
            pk = (2 * k + h < g_all) ? pk : ZPK;                              \
            const char* buf = tmpb + (PAR) * BUFB;                            \
            const uint2 q0 = *(const uint2*)(buf + (pk & 0xffffu));           \
            const uint2 q1 = *(const uint2*)(buf + (pk >> 16));               \
            float2 f0 = h2f2(q0.x), f1 = h2f2(q0.y);                          \
            float2 f2 = h2f2(q1.x), f3 = h2f2(q1.y);                          \
            d0a += f0.x + f2.x; d1a += f0.y + f2.y;                           \
            d2a += f1.x + f3.x; d3a += f1.y + f3.y;                           \
        }                                                                     \
        float d0 = d0a + d0b, d1 = d1a + d1b;                                 \
        float d2 = d2a + d2b, d3 = d3a + d3b;                                 \
        d0 = DPPADD(d0, 0xB1);   /* combine lane pair: VALU, no ds */         \
        d1 = DPPADD(d1, 0xB1);                                                \
        d2 = DPPADD(d2, 0xB1);                                                \
        d3 = DPPADD(d3, 0xB1);                                                \
        if (col == i) {                                                       \
            const float4 b0 = *(const float4*)(&backp[PAR][0]);               \
            const float4 b1 = *(const float4*)(&backp[PAR][4]);               \
            const float back = ((b0.x + b0.y) + (b0.z + b0.w)) +              \
                               ((b1.x + b1.y) + (b1.z + b1.w));               \
            if (e == 0) d0 = fmaf(back, 0.999f, d0);                          \
            else        d1 = fmaf(back, 0.999f, d1);                          \
        }                                                                     \
        D0 = d0; D1 = d1; D2 = d2; D3 = d3;                                   \
    }

#ifdef HAVE_FDOT2
#define GATHER8(q0, q1, SET)                                                  \
    d0##SET = __builtin_amdgcn_fdot2(bch2(q0.x), S10, d0##SET, false);        \
    d1##SET = __builtin_amdgcn_fdot2(bch2(q0.x), S01, d1##SET, false);        \
    d2##SET = __builtin_amdgcn_fdot2(bch2(q0.y), S10, d2##SET, false);        \
    d3##SET = __builtin_amdgcn_fdot2(bch2(q0.y), S01, d3##SET, false);        \
    d0##SET = __builtin_amdgcn_fdot2(bch2(q1.x), S10, d0##SET, false);        \
    d1##SET = __builtin_amdgcn_fdot2(bch2(q1.x), S01, d1##SET, false);        \
    d2##SET = __builtin_amdgcn_fdot2(bch2(q1.y), S10, d2##SET, false);        \
    d3##SET = __builtin_amdgcn_fdot2(bch2(q1.y), S01, d3##SET, false);
#else
#define GATHER8(q0, q1, SET)                                                  \
    {                                                                         \
        float2 f0 = h2f2(q0.x), f1 = h2f2(q0.y);                              \
        float2 f2 = h2f2(q1.x), f3 = h2f2(q1.y);                              \
        d0##SET += f0.x + f2.x; d1##SET += f0.y + f2.y;                       \
        d2##SET += f1.x + f3.x; d3##SET += f1.y + f3.y;                       \
    }
#endif

    for (int it = 0; it < steps; ) {
        STEP_BODY(0)
        ++it;
        if (it >= steps) break;
        STEP_BODY(1)
        ++it;
    }
#undef STEP_BODY
#undef GATHER8

    // final accept (h0 holds pacc and writes the output)
    float r4 = D0 * pcb[0];
    r4 = fmaf(D1, pcb[1], r4); r4 = fmaf(D2, pcb[2], r4); r4 = fmaf(D3, pcb[3], r4);
    if (h == 0) {
        acc += r4;
        out[((size_t)e * NN + i) * NN + col] = acc;
    }
}

// ---------------------------------------------------------------------------
extern "C" void kernel_launch(void* const* d_in, const int* in_sizes, int n_in,
                              void* d_out, int out_size, void* d_ws, size_t ws_size,
                              hipStream_t stream) {
    const float* vw  = (const float*)d_in[0];   // (N,N,V) fp32
    const float* adj = (const float*)d_in[1];   // (T,N,N) fp32 {0,1}
    const float* lrp = (const float*)d_in[2];   // (V,NTY,S,NAC) fp32
    const int* node_types = (const int*)d_in[3];
    const int* steps_p    = (const int*)d_in[4];

    float* ws       = (float*)d_ws;
    float* pol      = ws;                        // 1920 f
    float* inv_deg  = ws + 1920;                 // 768 f
    int*   gcnt     = (int*)(ws + 2688);         // 256 i
    unsigned* epk   = (unsigned*)(ws + 2944);    // CAPG*NN u32 = 48 KB
    int*   perm     = (int*)(ws + 2944 + CAPG * NN);  // 256 i

    k_setup<<<TT * NN + 64 + 1, 256, 0, stream>>>(adj, lrp, inv_deg, pol, epk, gcnt);
    k_sort<<<1, 256, 0, stream>>>(gcnt, perm);
    k_main<<<2 * NN, 512, 0, stream>>>(vw, node_types, pol, inv_deg, epk, gcnt,
                                       perm, steps_p, (float*)d_out);
}

// Round 10
// 152.616 us; speedup vs baseline: 1.0348x; 1.0348x over previous
//
#include <hip/hip_runtime.h>
#include <hip/hip_fp16.h>

// Problem constants
#define NN    256   // NUM_NODES
#define SS    4     // NUM_FSM_STATES
#define TT    3     // NUM_EDGE_TYPES
#define VV    4     // NUM_VARIANTS
#define NTY   8     // NUM_NODE_TYPES
#define NAC   15    // n_actions = T*S + 3
#define CAPG  48    // max packed pair-groups per col (96 edges; deg~Poi(38.4))
#define CAPE  (CAPG * 2)
#define ROWB  40    // bytes per tmp row (12 halves used + pad) -- r1-verified
#define ZROWB (NN * ROWB)       // zero pad row byte offset = 10240 (fits u16)
#define BUFB  (ZROWB + ROWB)    // bytes per tmp buffer = 10280 (8-aligned)
#define ZPK   ((unsigned)ZROWB | ((unsigned)ZROWB << 16))
#define GMR   16    // per-thread (per-parity-half) group regs; covers wave-max ~14

typedef _Float16 h2v __attribute__((ext_vector_type(2)));

#if defined(__has_builtin)
#if __has_builtin(__builtin_amdgcn_fdot2)
#define HAVE_FDOT2 1
#endif
#endif

static __device__ __forceinline__ unsigned ph2(float a, float b) {
    union { __half2 h; unsigned u; } c;
    c.h = __floats2half2_rn(a, b);
    return c.u;
}
static __device__ __forceinline__ h2v bch2(unsigned u) {
    union { unsigned u; h2v h; } c; c.u = u; return c.h;
}
static __device__ __forceinline__ float2 h2f2(unsigned u) {
    union { unsigned u; __half2 h; } c; c.u = u; return __half22float2(c.h);
}

// DPP-based lane combine: x + x[permuted lane], pure VALU (no ds_bpermute).
// quad_perm [1,0,3,2] = 0xB1 (xor1), [2,3,0,1] = 0x4E (xor2),
// row_ror:4 = 0x124, row_ror:8 = 0x128 (bijective within 16-lane row ->
// full-row sum in every lane), row_bcast15 = 0x142, row_bcast31 = 0x143.
// After ror stages + bcast15 + bcast31, lane 63 holds the 64-lane total
// (lanes 32..47 hold garbage -- never read).  bound_ctrl=true: no-src -> 0.
#define DPPADD(x, ctrl)                                                       \
    ((x) + __int_as_float(__builtin_amdgcn_update_dpp(                        \
               0, __float_as_int(x), (ctrl), 0xF, 0xF, true)))

// ---------------------------------------------------------------------------
// Setup (r5-verified):
//   blocks 0..767      : inv_deg row sums (coalesced, wave+LDS reduce)
//   blocks 768..831    : per-col edge build, 4 cols/block via float4 reads
//   block  832         : routing softmax
__global__ void k_setup(const float* __restrict__ adj,
                        const float* __restrict__ lrp,
                        float* __restrict__ inv_deg,
                        float* __restrict__ pol,
                        unsigned* __restrict__ epk,
                        int* __restrict__ gcnt) {
    const int b = blockIdx.x;
    const int tid = threadIdx.x;

    if (b < TT * NN) {
        __shared__ float wsum[4];
        float s = adj[(size_t)b * NN + tid];
#pragma unroll
        for (int off = 32; off > 0; off >>= 1) s += __shfl_down(s, off, 64);
        if ((tid & 63) == 0) wsum[tid >> 6] = s;
        __syncthreads();
        if (tid == 0)
            inv_deg[b] = 1.0f / fmaxf(wsum[0] + wsum[1] + wsum[2] + wsum[3], 1.0f);
    } else if (b < TT * NN + 64) {
        // edge lists for 4 columns: thread row=tid tests (t,tid,c4..c4+3)
        __shared__ int cnt[4];
        __shared__ unsigned short offs[4][CAPE + 2];
        const int c4 = (b - TT * NN) * 4;
        if (tid < 4) cnt[tid] = 0;
        __syncthreads();
#pragma unroll
        for (int t = 0; t < TT; t++) {
            const float4 a4 = *(const float4*)(adj + ((size_t)t * NN + tid) * NN + c4);
            const float av[4] = {a4.x, a4.y, a4.z, a4.w};
#pragma unroll
            for (int c = 0; c < 4; c++) {
                if (av[c] != 0.f) {
                    int idx = atomicAdd(&cnt[c], 1);
                    if (idx < CAPE) offs[c][idx] = (unsigned short)(tid * ROWB + t * 8);
                }
            }
        }
        __syncthreads();
        const int c    = tid >> 6;       // one wave per column
        const int lane = tid & 63;
        int cc = cnt[c]; if (cc > CAPE) cc = CAPE;
        if (lane == 0 && (cc & 1)) offs[c][cc] = (unsigned short)ZROWB;  // pad odd
        __syncthreads();
        const int g = (cc + 1) >> 1;
        for (int gg = lane; gg < g; gg += 64)
            epk[(size_t)gg * NN + (c4 + c)] =
                (unsigned)offs[c][2 * gg] | ((unsigned)offs[c][2 * gg + 1] << 16);
        if (lane == 0) gcnt[c4 + c] = g;
    } else {
        if (tid < VV * NTY * SS) {
            float x[NAC]; float m = -3.4e38f;
#pragma unroll
            for (int a = 0; a < NAC; a++) { x[a] = lrp[tid * NAC + a]; m = fmaxf(m, x[a]); }
            float ssum = 0.f;
#pragma unroll
            for (int a = 0; a < NAC; a++) { x[a] = __expf(x[a] - m); ssum += x[a]; }
            float inv = 1.f / ssum;
#pragma unroll
            for (int a = 0; a < NAC; a++) pol[tid * NAC + a] = x[a] * inv;
        }
    }
}

// ---------------------------------------------------------------------------
// Degree sort (r5-verified, trivial): counting sort of the 256 cols by group
// count (ascending).  perm[rank] = col.
__global__ void k_sort(const int* __restrict__ gcnt, int* __restrict__ perm) {
    __shared__ int base[64];
    const int tid = threadIdx.x;
    if (tid < 64) base[tid] = 0;
    __syncthreads();
    const int g = gcnt[tid] & 63;
    atomicAdd(&base[g], 1);          // histogram
    __syncthreads();
    if (tid == 0) {
        int s = 0;
#pragma unroll
        for (int b = 0; b < 64; b++) { int c = base[b]; base[b] = s; s += c; }
    }
    __syncthreads();
    const int pos = atomicAdd(&base[g], 1);   // cursor within bin
    perm[pos] = tid;
}

// ---------------------------------------------------------------------------
// Main loop: grid 512 = (e,i); block 512 threads = 2 threads per col.
// r8-verified optimum (95.7us): degree-sorted cols, pre-split resident
// gather addresses, chunk-2 gather (4 b64 in flight; chunk-4 regressed r9:
// granule-of-4 rounding adds ~15-20% junk reads at kmax~10), x2-unrolled
// step loop (parity as ds immediate), DPP d-combine, b64+b32 phase-A writes.
// Kept from r9: fully-DPP bj reduce (row_bcast15/31; zero LDS ops, lane 63
// holds the wave total).
__global__ __launch_bounds__(512, 2) void k_main(
    const float* __restrict__ vw,
    const int* __restrict__ node_types,
    const float* __restrict__ pol,
    const float* __restrict__ inv_deg,
    const unsigned* __restrict__ epk,
    const int* __restrict__ gcnt,
    const int* __restrict__ perm,
    const int* __restrict__ steps_p,
    float* __restrict__ out)
{
    const int i    = blockIdx.x & 255;
    const int e    = blockIdx.x >> 8;
    const int tid  = threadIdx.x;
    const int col  = perm[tid >> 1];    // degree-sorted column assignment
    const int h    = tid & 1;
    const int lane = tid & 63;
    const int wv   = tid >> 6;          // 8 waves
    const int steps = steps_p[0];

    __shared__ __align__(16) char tmpb[2 * BUFB];   // 20.6 KB
    __shared__ __align__(16) float backp[2][8];

    if (tid < 20) {
        int pb = tid / 10, w = tid % 10;
        ((unsigned*)(tmpb + pb * BUFB + ZROWB))[w] = 0u;
    }

    // --- per-(col,half) mixed policy slice, pre-scaled by inv_deg ---
    const float4 w4 = *(const float4*)(vw + ((size_t)i * NN + col) * VV);
    const float wvv[VV] = {w4.x, w4.y, w4.z, w4.w};
    const int ntj = node_types[col];
    const int ab  = h * 6;              // this half's action base
    float pm6[SS][6], pcb[SS];
#pragma unroll
    for (int s = 0; s < SS; s++) {
        pcb[s] = 0.f;
#pragma unroll
        for (int a = 0; a < 6; a++) pm6[s][a] = 0.f;
    }
#pragma unroll
    for (int v = 0; v < VV; v++) {
        const float* pr = pol + (size_t)(v * NTY + ntj) * SS * NAC;
#pragma unroll
        for (int s = 0; s < SS; s++) {
            const float* p = pr + s * NAC;
#pragma unroll
            for (int a = 0; a < 6; a++) pm6[s][a] = fmaf(wvv[v], p[ab + a], pm6[s][a]);
            pcb[s] = fmaf(wvv[v], p[12 + h], pcb[s]);   // h0: accept, h1: back
        }
    }
    {
        float invd[TT];
#pragma unroll
        for (int t = 0; t < TT; t++) invd[t] = inv_deg[t * NN + col];
#pragma unroll
        for (int s = 0; s < SS; s++)
#pragma unroll
            for (int a = 0; a < 6; a++) pm6[s][a] *= invd[(ab + a) >> 2];
    }

    float D0 = (0 == e && col == i) ? 1.f : 0.f;
    float D1 = (1 == e && col == i) ? 1.f : 0.f;
    float D2 = 0.f, D3 = 0.f;
    float acc = 0.f;

    // --- this half's edge list (groups with parity h), pre-split addresses ---
    const int g_all = gcnt[col];
    const int ch = (g_all - h + 1) >> 1;     // my group count
    int km = ch;
#pragma unroll
    for (int off = 32; off > 0; off >>= 1) {
        int o = __shfl_xor(km, off, 64);
        km = o > km ? o : km;
    }
    const int kmax = __builtin_amdgcn_readfirstlane(km);   // wave-uniform

    unsigned offA[GMR], offB[GMR];      // 32 VGPR: LDS byte offsets, base-free
#pragma unroll
    for (int k = 0; k < GMR; k++) {
        unsigned pk = epk[(size_t)(2 * k + h) * NN + col];  // in-bounds; junk past g_all
        pk = (2 * k + h < g_all) ? pk : ZPK;                // junk reads zero row (bcast)
        offA[k] = pk & 0xffffu;
        offB[k] = pk >> 16;
    }

    const h2v S10 = {(_Float16)1.0f, (_Float16)0.0f};
    const h2v S01 = {(_Float16)0.0f, (_Float16)1.0f};
    // phase-A write addresses (branch-free split): b64 at +16h, b32 at +8+4h
    char* const myrowA = tmpb + col * ROWB + 16 * h;   // 8-aligned both h
    char* const myrowB = tmpb + col * ROWB + 8 + 4 * h;

#define STEP_BODY(PAR)                                                        \
    {                                                                         \
        float r4 = D0 * pcb[0];                                               \
        r4 = fmaf(D1, pcb[1], r4); r4 = fmaf(D2, pcb[2], r4);                 \
        r4 = fmaf(D3, pcb[3], r4);                                            \
        if (h == 0) acc += r4;                                                \
        float bj = h ? r4 : 0.f;                                              \
        float tv[6];                                                          \
        _Pragma("unroll")                                                     \
        for (int a = 0; a < 6; a++) {                                         \
            float x = D0 * pm6[0][a];                                         \
            x = fmaf(D1, pm6[1][a], x);                                       \
            x = fmaf(D2, pm6[2][a], x);                                       \
            x = fmaf(D3, pm6[3][a], x);                                       \
            tv[a] = x;                                                        \
        }                                                                     \
        {                                                                     \
            const unsigned wx = ph2(tv[0], tv[1]);                            \
            const unsigned wy = ph2(tv[2], tv[3]);                            \
            const unsigned wz = ph2(tv[4], tv[5]);                            \
            const unsigned lo = h ? wy : wx;                                  \
            const unsigned hi = h ? wz : wy;                                  \
            const unsigned bb = h ? wx : wz;                                  \
            *(unsigned long long*)(myrowA + (PAR) * BUFB) =                   \
                (unsigned long long)lo | ((unsigned long long)hi << 32);      \
            *(unsigned*)(myrowB + (PAR) * BUFB) = bb;                         \
        }                                                                     \
        bj = DPPADD(bj, 0xB1);    /* xor1 (quad_perm)            */           \
        bj = DPPADD(bj, 0x4E);    /* xor2 (quad_perm)            */           \
        bj = DPPADD(bj, 0x124);   /* row_ror:4                   */           \
        bj = DPPADD(bj, 0x128);   /* row_ror:8 -> row sums       */           \
        bj = DPPADD(bj, 0x142);   /* row_bcast15: chain rows     */           \
        bj = DPPADD(bj, 0x143);   /* row_bcast31: lane63 = total */           \
        if (lane == 63) backp[PAR][wv] = bj;                                  \
        __syncthreads();                                                      \
        float d0a = 0.f, d1a = 0.f, d2a = 0.f, d3a = 0.f;                     \
        float d0b = 0.f, d1b = 0.f, d2b = 0.f, d3b = 0.f;                     \
        _Pragma("unroll")                                                     \
        for (int kc = 0; kc < GMR; kc += 2) {                                 \
            if (kc < kmax) {   /* kmax in SGPR -> scalar branch */            \
                const uint2 qA0 = *(const uint2*)(tmpb + (PAR) * BUFB + offA[kc]);     \
                const uint2 qA1 = *(const uint2*)(tmpb + (PAR) * BUFB + offB[kc]);     \
                const uint2 qB0 = *(const uint2*)(tmpb + (PAR) * BUFB + offA[kc + 1]); \
                const uint2 qB1 = *(const uint2*)(tmpb + (PAR) * BUFB + offB[kc + 1]); \
                GATHER8(qA0, qA1, a)                                          \
                GATHER8(qB0, qB1, b)                                          \
            }                                                                 \
        }                                                                     \
        for (int k = GMR; k < kmax; k++) {                                    \
            unsigned pk = epk[(size_t)(2 * k + h) * NN + col];                \
            pk = (2 * k + h < g_all) ? pk : ZPK;                              \
            const char* buf = tmpb + (PAR) * BUFB;                            \
            const uint2 q0 = *(const uint2*)(buf + (pk & 0xffffu));           \
            const uint2 q1 = *(const uint2*)(buf + (pk >> 16));               \
            float2 f0 = h2f2(q0.x), f1 = h2f2(q0.y);                          \
            float2 f2 = h2f2(q1.x), f3 = h2f2(q1.y);                          \
            d0a += f0.x + f2.x; d1a += f0.y + f2.y;                           \
            d2a += f1.x + f3.x; d3a += f1.y + f3.y;                           \
        }                                                                     \
        float d0 = d0a + d0b, d1 = d1a + d1b;                                 \
        float d2 = d2a + d2b, d3 = d3a + d3b;                                 \
        d0 = DPPADD(d0, 0xB1);   /* combine lane pair: VALU, no ds */         \
        d1 = DPPADD(d1, 0xB1);                                                \
        d2 = DPPADD(d2, 0xB1);                                                \
        d3 = DPPADD(d3, 0xB1);                                                \
        if (col == i) {                                                       \
            const float4 b0 = *(const float4*)(&backp[PAR][0]);               \
            const float4 b1 = *(const float4*)(&backp[PAR][4]);               \
            const float back = ((b0.x + b0.y) + (b0.z + b0.w)) +              \
                               ((b1.x + b1.y) + (b1.z + b1.w));               \
            if (e == 0) d0 = fmaf(back, 0.999f, d0);                          \
            else        d1 = fmaf(back, 0.999f, d1);                          \
        }                                                                     \
        D0 = d0; D1 = d1; D2 = d2; D3 = d3;                                   \
    }

#ifdef HAVE_FDOT2
#define GATHER8(q0, q1, SET)                                                  \
    d0##SET = __builtin_amdgcn_fdot2(bch2(q0.x), S10, d0##SET, false);        \
    d1##SET = __builtin_amdgcn_fdot2(bch2(q0.x), S01, d1##SET, false);        \
    d2##SET = __builtin_amdgcn_fdot2(bch2(q0.y), S10, d2##SET, false);        \
    d3##SET = __builtin_amdgcn_fdot2(bch2(q0.y), S01, d3##SET, false);        \
    d0##SET = __builtin_amdgcn_fdot2(bch2(q1.x), S10, d0##SET, false);        \
    d1##SET = __builtin_amdgcn_fdot2(bch2(q1.x), S01, d1##SET, false);        \
    d2##SET = __builtin_amdgcn_fdot2(bch2(q1.y), S10, d2##SET, false);        \
    d3##SET = __builtin_amdgcn_fdot2(bch2(q1.y), S01, d3##SET, false);
#else
#define GATHER8(q0, q1, SET)                                                  \
    {                                                                         \
        float2 f0 = h2f2(q0.x), f1 = h2f2(q0.y);                              \
        float2 f2 = h2f2(q1.x), f3 = h2f2(q1.y);                              \
        d0##SET += f0.x + f2.x; d1##SET += f0.y + f2.y;                       \
        d2##SET += f1.x + f3.x; d3##SET += f1.y + f3.y;                       \
    }
#endif

    for (int it = 0; it < steps; ) {
        STEP_BODY(0)
        ++it;
        if (it >= steps) break;
        STEP_BODY(1)
        ++it;
    }
#undef STEP_BODY
#undef GATHER8

    // final accept (h0 holds pacc and writes the output)
    float r4 = D0 * pcb[0];
    r4 = fmaf(D1, pcb[1], r4); r4 = fmaf(D2, pcb[2], r4); r4 = fmaf(D3, pcb[3], r4);
    if (h == 0) {
        acc += r4;
        out[((size_t)e * NN + i) * NN + col] = acc;
    }
}

// ---------------------------------------------------------------------------
extern "C" void kernel_launch(void* const* d_in, const int* in_sizes, int n_in,
                              void* d_out, int out_size, void* d_ws, size_t ws_size,
                              hipStream_t stream) {
    const float* vw  = (const float*)d_in[0];   // (N,N,V) fp32
    const float* adj = (const float*)d_in[1];   // (T,N,N) fp32 {0,1}
    const float* lrp = (const float*)d_in[2];   // (V,NTY,S,NAC) fp32
    const int* node_types = (const int*)d_in[3];
    const int* steps_p    = (const int*)d_in[4];

    float* ws       = (float*)d_ws;
    float* pol      = ws;                        // 1920 f
    float* inv_deg  = ws + 1920;                 // 768 f
    int*   gcnt     = (int*)(ws + 2688);         // 256 i
    unsigned* epk   = (unsigned*)(ws + 2944);    // CAPG*NN u32 = 48 KB
    int*   perm     = (int*)(ws + 2944 + CAPG * NN);  // 256 i

    k_setup<<<TT * NN + 64 + 1, 256, 0, stream>>>(adj, lrp, inv_deg, pol, epk, gcnt);
    k_sort<<<1, 256, 0, stream>>>(gcnt, perm);
    k_main<<<2 * NN, 512, 0, stream>>>(vw, node_types, pol, inv_deg, epk, gcnt,
                                       perm, steps_p, (float*)d_out);
}